// Round 4
// baseline (32746.283 us; speedup 1.0000x reference)
//
#include <hip/hip_runtime.h>
#include <cstdint>

// GRU persistent kernel v4: T=512, B=64, I=512, H=1024, O=512, fp32.
// Grid 256 = 128 j-tiles x 2 batch-halves, 1024 threads (16 waves, 4/SIMD).
// h-gate weights (96 KB fp32) in swizzled LDS; x-gate weights pre-transposed
// [j][k] streamed; W_out streamed raw. Two independent barrier groups
// (per batch-half), relaxed-spin + single acquire fence. Phases per step:
//   A : r = sigmoid(h@W_rh + xr_pre + b_r); s = r*h        -> arrive(A)
//   A2: z = sigmoid(h@W_zh + xz_pre + b_z); y_{t-1}=h@Wout -> wait(A)
//   B : ht = tanh(s@W_hh + xh_pre + b_h); h += z*(ht-h)    -> arrive(B)
//   C : xr/xz/xh_pre for step t+1 (x only, hides barrier B) -> wait(B)

#define TT 512
#define BB 64
#define II 512
#define HH 1024
#define OO 512
#define NTHR 1024

typedef float4 f4;
__device__ __forceinline__ f4 ld4(const float* p){ return *reinterpret_cast<const f4*>(p); }
// weight-read rows have k-stride 8 (ksec in [0,128)); 8 lane-groups per wave
// span k%64 in {0,8,..,56}: XOR bit2 of float index with bit5 of k -> all 8
// bank-quads distinct, f4 stays contiguous (bits 0-1 untouched).
__device__ __forceinline__ int swz(int k){ return k ^ (((k >> 5) & 1) << 2); }

// ---------------- one-time prep kernels ----------------
__global__ void k_transpose_x(const float* __restrict__ x, float* __restrict__ xT){
  // x[t][b][i] -> xT[t][i][b]
  size_t total = (size_t)TT * II * BB;
  for (size_t n = (size_t)blockIdx.x * blockDim.x + threadIdx.x; n < total;
       n += (size_t)gridDim.x * blockDim.x){
    size_t t = n / ((size_t)II * BB);
    size_t rem = n % ((size_t)II * BB);
    size_t i = rem / BB, b = rem % BB;
    xT[n] = x[(t * BB + b) * II + i];
  }
}

__global__ void k_transpose_wx(const float* __restrict__ W, float* __restrict__ WT){
  // W[k][j] (I x H) -> WT[j][k] (H x I)
  size_t n = (size_t)blockIdx.x * blockDim.x + threadIdx.x;
  if (n >= (size_t)II * HH) return;
  size_t j = n / II, k = n % II;
  WT[n] = W[k * HH + j];
}

__global__ void k_transpose_h0(const float* __restrict__ st, float* __restrict__ h0){
  // state[b][j] -> h0[j][b]
  size_t n = (size_t)blockIdx.x * blockDim.x + threadIdx.x;
  if (n >= (size_t)HH * BB) return;
  size_t j = n / BB, b = n % BB;
  h0[n] = st[b * HH + j];
}

__global__ void k_init_bars(unsigned* bars){
  if (threadIdx.x < 512) bars[threadIdx.x] = 0;
}

// ---------------- barrier (per batch-half group of 128 blocks) ----------------
__device__ __forceinline__ void g_arrive(unsigned* bars, int g, int jt, unsigned ep){
  __builtin_amdgcn_fence(__ATOMIC_RELEASE, "agent");
  unsigned* leaf = bars + (g * 9 + (jt & 7)) * 16;
  unsigned old = __hip_atomic_fetch_add(leaf, 1u, __ATOMIC_RELAXED, __HIP_MEMORY_SCOPE_AGENT);
  if (old + 1u == ep * 16u)
    __hip_atomic_fetch_add(bars + (g * 9 + 8) * 16, 1u, __ATOMIC_RELAXED, __HIP_MEMORY_SCOPE_AGENT);
}
__device__ __forceinline__ void g_wait(unsigned* bars, int g, unsigned ep){
  unsigned* root = bars + (g * 9 + 8) * 16;
  while (__hip_atomic_load(root, __ATOMIC_RELAXED, __HIP_MEMORY_SCOPE_AGENT) < ep * 8u)
    __builtin_amdgcn_s_sleep(1);
  __builtin_amdgcn_fence(__ATOMIC_ACQUIRE, "agent");
}

// reduce over the 3 in-wave ksec bits (lanes xor 8,16,32)
#define WREDUCE(v) { v += __shfl_xor(v, 8); v += __shfl_xor(v, 16); v += __shfl_xor(v, 32); }

// ---------------- the persistent GRU kernel ----------------
__global__ __launch_bounds__(NTHR, 4) void k_gru(
    const float* __restrict__ xT,
    const float* __restrict__ WxTr, const float* __restrict__ WxTz, const float* __restrict__ WxTh,
    float* __restrict__ h, float* __restrict__ s,
    const float* __restrict__ W_zh, const float* __restrict__ b_z,
    const float* __restrict__ W_rh, const float* __restrict__ b_r,
    const float* __restrict__ W_hh, const float* __restrict__ b_h,
    const float* __restrict__ W_out, const float* __restrict__ b_out,
    float* __restrict__ out, unsigned* __restrict__ bars)
{
  __shared__ float sW[3 * 8 * 1024];   // [g:0=RH,1=ZH,2=HH][c<8][k swz]  96 KB
  __shared__ float red[16 * 528];      // cross-wave reduce                33.8 KB
  __shared__ float xpre[3][256];       // x-projections for current step
  __shared__ float sZ[256];            // z gate
  __shared__ float sBias[32];          // b_r[8] b_z[8] b_h[8] b_out[4]

  const int tid = threadIdx.x;
  const int bid = blockIdx.x;
  const int jt = bid & 127, bhalf = bid >> 7;
  const int j0 = jt * 8, o0 = jt * 4, bbase = bhalf * 32;

  // ---- prologue: weight slices -> swizzled LDS ----
  {
    const int k = tid;                     // 0..1023
    f4 vr  = ld4(W_rh + (size_t)k * HH + j0);
    f4 vr2 = ld4(W_rh + (size_t)k * HH + j0 + 4);
    f4 vz  = ld4(W_zh + (size_t)k * HH + j0);
    f4 vz2 = ld4(W_zh + (size_t)k * HH + j0 + 4);
    f4 vh  = ld4(W_hh + (size_t)k * HH + j0);
    f4 vh2 = ld4(W_hh + (size_t)k * HH + j0 + 4);
    const int kx = swz(k);
    float ar[8] = {vr.x,vr.y,vr.z,vr.w,vr2.x,vr2.y,vr2.z,vr2.w};
    float az[8] = {vz.x,vz.y,vz.z,vz.w,vz2.x,vz2.y,vz2.z,vz2.w};
    float ah[8] = {vh.x,vh.y,vh.z,vh.w,vh2.x,vh2.y,vh2.z,vh2.w};
    #pragma unroll
    for (int c = 0; c < 8; ++c){
      sW[0*8192 + c*1024 + kx] = ar[c];
      sW[1*8192 + c*1024 + kx] = az[c];
      sW[2*8192 + c*1024 + kx] = ah[c];
    }
  }
  if (tid < 8){
    sBias[tid]      = b_r[j0 + tid];
    sBias[8 + tid]  = b_z[j0 + tid];
    sBias[16 + tid] = b_h[j0 + tid];
    if (tid < 4) sBias[24 + tid] = b_out[o0 + tid];
  }

  const int bg = tid & 7, b0 = bbase + bg * 4;
  const int ksec = tid >> 3;           // 0..127
  const int wv = tid >> 6;             // wave 0..15
  const bool wr0 = ((tid & 56) == 0);  // (ksec & 7) == 0
  const int kh0 = ksec * 8;            // K=1024 / 128
  const int kx0 = ksec * 4;            // K=512  / 128
  __syncthreads();

  for (int t = -1; t < TT; ++t){
    f4 st4[8];                         // h stash, A -> A2
    if (t >= 0){
      // ================= A: r gate =================
      float aR[8][4] = {};
      const float* hb = h + kh0 * BB + b0;
      #pragma unroll
      for (int i4 = 0; i4 < 2; ++i4){
        #pragma unroll
        for (int kk = 0; kk < 4; ++kk) st4[i4*4+kk] = ld4(hb + (i4*4+kk) * BB);
        const int kxc = swz(kh0 + i4*4);
        #pragma unroll
        for (int c = 0; c < 8; ++c){
          f4 wf = *reinterpret_cast<const f4*>(&sW[0*8192 + c*1024 + kxc]);
          float wvv[4] = {wf.x, wf.y, wf.z, wf.w};
          #pragma unroll
          for (int kk = 0; kk < 4; ++kk){
            const f4 hv = st4[i4*4+kk];
            aR[c][0] = fmaf(wvv[kk], hv.x, aR[c][0]);
            aR[c][1] = fmaf(wvv[kk], hv.y, aR[c][1]);
            aR[c][2] = fmaf(wvv[kk], hv.z, aR[c][2]);
            aR[c][3] = fmaf(wvv[kk], hv.w, aR[c][3]);
          }
        }
      }
      #pragma unroll
      for (int c = 0; c < 8; ++c)
        #pragma unroll
        for (int bb = 0; bb < 4; ++bb) WREDUCE(aR[c][bb]);
      if (wr0)
        #pragma unroll
        for (int c = 0; c < 8; ++c)
          #pragma unroll
          for (int bb = 0; bb < 4; ++bb)
            red[wv*528 + c*32 + bg*4 + bb] = aR[c][bb];
      __syncthreads();
      if (tid < 256){
        float sum = 0.f;
        #pragma unroll
        for (int w = 0; w < 16; ++w) sum += red[w*528 + tid];
        const int c = tid >> 5, bl = tid & 31;
        const float v = sum + xpre[0][tid] + sBias[c];
        const float rr = 1.f / (1.f + expf(-v));
        const int jg = j0 + c, bgl = bbase + bl;
        s[jg*BB + bgl] = rr * h[jg*BB + bgl];
      }
      __syncthreads();
      if (tid == 0) g_arrive(bars, bhalf, jt, 2*t + 1);

      // ================= A2: z gate + y_{t-1} (hides barrier A) =================
      float aZ[8][4] = {};
      float aY[4][4] = {};
      #pragma unroll
      for (int i4 = 0; i4 < 2; ++i4){
        const int kc = kh0 + i4*4;
        const int kxc = swz(kc);
        #pragma unroll
        for (int c = 0; c < 8; ++c){
          f4 wf = *reinterpret_cast<const f4*>(&sW[1*8192 + c*1024 + kxc]);
          float wvv[4] = {wf.x, wf.y, wf.z, wf.w};
          #pragma unroll
          for (int kk = 0; kk < 4; ++kk){
            const f4 hv = st4[i4*4+kk];
            aZ[c][0] = fmaf(wvv[kk], hv.x, aZ[c][0]);
            aZ[c][1] = fmaf(wvv[kk], hv.y, aZ[c][1]);
            aZ[c][2] = fmaf(wvv[kk], hv.z, aZ[c][2]);
            aZ[c][3] = fmaf(wvv[kk], hv.w, aZ[c][3]);
          }
        }
        #pragma unroll
        for (int oc = 0; oc < 4; ++oc){
          f4 wo = ld4(W_out + (size_t)(o0 + oc) * HH + kc);
          float wvv[4] = {wo.x, wo.y, wo.z, wo.w};
          #pragma unroll
          for (int kk = 0; kk < 4; ++kk){
            const f4 hv = st4[i4*4+kk];
            aY[oc][0] = fmaf(wvv[kk], hv.x, aY[oc][0]);
            aY[oc][1] = fmaf(wvv[kk], hv.y, aY[oc][1]);
            aY[oc][2] = fmaf(wvv[kk], hv.z, aY[oc][2]);
            aY[oc][3] = fmaf(wvv[kk], hv.w, aY[oc][3]);
          }
        }
      }
      #pragma unroll
      for (int c = 0; c < 8; ++c)
        #pragma unroll
        for (int bb = 0; bb < 4; ++bb) WREDUCE(aZ[c][bb]);
      #pragma unroll
      for (int oc = 0; oc < 4; ++oc)
        #pragma unroll
        for (int bb = 0; bb < 4; ++bb) WREDUCE(aY[oc][bb]);
      if (wr0){
        #pragma unroll
        for (int c = 0; c < 8; ++c)
          #pragma unroll
          for (int bb = 0; bb < 4; ++bb)
            red[wv*528 + c*32 + bg*4 + bb] = aZ[c][bb];
        #pragma unroll
        for (int oc = 0; oc < 4; ++oc)
          #pragma unroll
          for (int bb = 0; bb < 4; ++bb)
            red[wv*528 + 256 + oc*32 + bg*4 + bb] = aY[oc][bb];
      }
      __syncthreads();
      if (tid < 256){
        float sum = 0.f;
        #pragma unroll
        for (int w = 0; w < 16; ++w) sum += red[w*528 + tid];
        const int c = tid >> 5;
        sZ[tid] = 1.f / (1.f + expf(-(sum + xpre[1][tid] + sBias[8 + c])));
      } else if (tid < 384){
        const int idx = tid - 256;
        float sum = 0.f;
        #pragma unroll
        for (int w = 0; w < 16; ++w) sum += red[w*528 + tid];
        const int oc = idx >> 5, bl = idx & 31;
        if (t > 0)
          out[((size_t)(t-1)*BB + bbase + bl)*OO + o0 + oc] = sum + sBias[24 + oc];
      }
      if (tid == 0) g_wait(bars, bhalf, 2*t + 1);
      __syncthreads();

      // ================= B: candidate + h update =================
      float aH[8][4] = {};
      const float* sb = s + kh0 * BB + b0;
      #pragma unroll
      for (int i4 = 0; i4 < 2; ++i4){
        f4 sv4[4];
        #pragma unroll
        for (int kk = 0; kk < 4; ++kk) sv4[kk] = ld4(sb + (i4*4+kk) * BB);
        const int kxc = swz(kh0 + i4*4);
        #pragma unroll
        for (int c = 0; c < 8; ++c){
          f4 wf = *reinterpret_cast<const f4*>(&sW[2*8192 + c*1024 + kxc]);
          float wvv[4] = {wf.x, wf.y, wf.z, wf.w};
          #pragma unroll
          for (int kk = 0; kk < 4; ++kk){
            aH[c][0] = fmaf(wvv[kk], sv4[kk].x, aH[c][0]);
            aH[c][1] = fmaf(wvv[kk], sv4[kk].y, aH[c][1]);
            aH[c][2] = fmaf(wvv[kk], sv4[kk].z, aH[c][2]);
            aH[c][3] = fmaf(wvv[kk], sv4[kk].w, aH[c][3]);
          }
        }
      }
      #pragma unroll
      for (int c = 0; c < 8; ++c)
        #pragma unroll
        for (int bb = 0; bb < 4; ++bb) WREDUCE(aH[c][bb]);
      if (wr0)
        #pragma unroll
        for (int c = 0; c < 8; ++c)
          #pragma unroll
          for (int bb = 0; bb < 4; ++bb)
            red[wv*528 + c*32 + bg*4 + bb] = aH[c][bb];
      __syncthreads();
      if (tid < 256){
        float sum = 0.f;
        #pragma unroll
        for (int w = 0; w < 16; ++w) sum += red[w*528 + tid];
        const int c = tid >> 5, bl = tid & 31;
        const int jg = j0 + c, bgl = bbase + bl;
        const float ht = tanhf(sum + xpre[2][tid] + sBias[16 + c]);
        const float z = sZ[tid];
        const float hold = h[jg*BB + bgl];
        const float hnew = fmaf(z, ht - hold, hold);
        h[jg*BB + bgl] = hnew;
        if (t == TT - 1) out[(size_t)TT*BB*OO + (size_t)bgl*HH + jg] = hnew;
      }
      __syncthreads();
      if (tid == 0) g_arrive(bars, bhalf, jt, 2*t + 2);
    }

    // ================= C: x-projections for step t+1 (hides barrier B) ===========
    if (t + 1 < TT){
      const int tc = t + 1;
      const float* xb = xT + (size_t)tc * II * BB + kx0 * BB + b0;
      f4 xv4[4];
      #pragma unroll
      for (int kk = 0; kk < 4; ++kk) xv4[kk] = ld4(xb + kk * BB);

      // pass 1: r & z projections
      {
        float aXr[8][4] = {}, aXz[8][4] = {};
        #pragma unroll
        for (int c = 0; c < 8; ++c){
          f4 wr_ = ld4(WxTr + (size_t)(j0 + c) * II + kx0);
          f4 wz_ = ld4(WxTz + (size_t)(j0 + c) * II + kx0);
          float wrv[4] = {wr_.x, wr_.y, wr_.z, wr_.w};
          float wzv[4] = {wz_.x, wz_.y, wz_.z, wz_.w};
          #pragma unroll
          for (int kk = 0; kk < 4; ++kk){
            const f4 xv = xv4[kk];
            aXr[c][0] = fmaf(wrv[kk], xv.x, aXr[c][0]);
            aXr[c][1] = fmaf(wrv[kk], xv.y, aXr[c][1]);
            aXr[c][2] = fmaf(wrv[kk], xv.z, aXr[c][2]);
            aXr[c][3] = fmaf(wrv[kk], xv.w, aXr[c][3]);
            aXz[c][0] = fmaf(wzv[kk], xv.x, aXz[c][0]);
            aXz[c][1] = fmaf(wzv[kk], xv.y, aXz[c][1]);
            aXz[c][2] = fmaf(wzv[kk], xv.z, aXz[c][2]);
            aXz[c][3] = fmaf(wzv[kk], xv.w, aXz[c][3]);
          }
        }
        #pragma unroll
        for (int c = 0; c < 8; ++c)
          #pragma unroll
          for (int bb = 0; bb < 4; ++bb){ WREDUCE(aXr[c][bb]); WREDUCE(aXz[c][bb]); }
        if (wr0)
          #pragma unroll
          for (int c = 0; c < 8; ++c)
            #pragma unroll
            for (int bb = 0; bb < 4; ++bb){
              red[wv*528 + c*32 + bg*4 + bb]       = aXr[c][bb];
              red[wv*528 + 256 + c*32 + bg*4 + bb] = aXz[c][bb];
            }
      }
      __syncthreads();
      if (tid < 512){
        float sum = 0.f;
        #pragma unroll
        for (int w = 0; w < 16; ++w) sum += red[w*528 + tid];
        if (tid < 256) xpre[0][tid] = sum;
        else           xpre[1][tid - 256] = sum;
      }
      __syncthreads();

      // pass 2: h projection
      {
        float aXh[8][4] = {};
        #pragma unroll
        for (int c = 0; c < 8; ++c){
          f4 wh_ = ld4(WxTh + (size_t)(j0 + c) * II + kx0);
          float whv[4] = {wh_.x, wh_.y, wh_.z, wh_.w};
          #pragma unroll
          for (int kk = 0; kk < 4; ++kk){
            const f4 xv = xv4[kk];
            aXh[c][0] = fmaf(whv[kk], xv.x, aXh[c][0]);
            aXh[c][1] = fmaf(whv[kk], xv.y, aXh[c][1]);
            aXh[c][2] = fmaf(whv[kk], xv.z, aXh[c][2]);
            aXh[c][3] = fmaf(whv[kk], xv.w, aXh[c][3]);
          }
        }
        #pragma unroll
        for (int c = 0; c < 8; ++c)
          #pragma unroll
          for (int bb = 0; bb < 4; ++bb) WREDUCE(aXh[c][bb]);
        if (wr0)
          #pragma unroll
          for (int c = 0; c < 8; ++c)
            #pragma unroll
            for (int bb = 0; bb < 4; ++bb)
              red[wv*528 + c*32 + bg*4 + bb] = aXh[c][bb];
      }
      __syncthreads();
      if (tid < 256){
        float sum = 0.f;
        #pragma unroll
        for (int w = 0; w < 16; ++w) sum += red[w*528 + tid];
        xpre[2][tid] = sum;
      }
      __syncthreads();
    }

    if (t >= 0){
      if (tid == 0) g_wait(bars, bhalf, 2*t + 2);
      __syncthreads();
    }
  }

  // ================= trailing y_{T-1} from final h =================
  {
    float aY[4][4] = {};
    const float* hb = h + kh0 * BB + b0;
    #pragma unroll
    for (int i4 = 0; i4 < 2; ++i4){
      f4 hv4[4];
      #pragma unroll
      for (int kk = 0; kk < 4; ++kk) hv4[kk] = ld4(hb + (i4*4+kk) * BB);
      const int kc = kh0 + i4*4;
      #pragma unroll
      for (int oc = 0; oc < 4; ++oc){
        f4 wo = ld4(W_out + (size_t)(o0 + oc) * HH + kc);
        float wvv[4] = {wo.x, wo.y, wo.z, wo.w};
        #pragma unroll
        for (int kk = 0; kk < 4; ++kk){
          aY[oc][0] = fmaf(wvv[kk], hv4[kk].x, aY[oc][0]);
          aY[oc][1] = fmaf(wvv[kk], hv4[kk].y, aY[oc][1]);
          aY[oc][2] = fmaf(wvv[kk], hv4[kk].z, aY[oc][2]);
          aY[oc][3] = fmaf(wvv[kk], hv4[kk].w, aY[oc][3]);
        }
      }
    }
    #pragma unroll
    for (int oc = 0; oc < 4; ++oc)
      #pragma unroll
      for (int bb = 0; bb < 4; ++bb) WREDUCE(aY[oc][bb]);
    if (wr0)
      #pragma unroll
      for (int oc = 0; oc < 4; ++oc)
        #pragma unroll
        for (int bb = 0; bb < 4; ++bb)
          red[wv*528 + oc*32 + bg*4 + bb] = aY[oc][bb];
    __syncthreads();
    if (tid < 128){
      float sum = 0.f;
      #pragma unroll
      for (int w = 0; w < 16; ++w) sum += red[w*528 + tid];
      const int oc = tid >> 5, bl = tid & 31;
      out[((size_t)(TT-1)*BB + bbase + bl)*OO + o0 + oc] = sum + sBias[24 + oc];
    }
  }
}

// ---------------- host ----------------
extern "C" void kernel_launch(void* const* d_in, const int* in_sizes, int n_in,
                              void* d_out, int out_size, void* d_ws, size_t ws_size,
                              hipStream_t stream) {
  const float* x     = (const float*)d_in[0];
  const float* st    = (const float*)d_in[1];
  const float* W_zh  = (const float*)d_in[2];
  const float* W_zx  = (const float*)d_in[3];
  const float* b_z   = (const float*)d_in[4];
  const float* W_rh  = (const float*)d_in[5];
  const float* W_rx  = (const float*)d_in[6];
  const float* b_r   = (const float*)d_in[7];
  const float* W_hh  = (const float*)d_in[8];
  const float* W_hx  = (const float*)d_in[9];
  const float* b_h   = (const float*)d_in[10];
  const float* W_out = (const float*)d_in[11];
  const float* b_out = (const float*)d_in[12];
  float* out = (float*)d_out;
  float* ws  = (float*)d_ws;

  const size_t xT_sz = (size_t)TT * II * BB;   // 16,777,216
  const size_t wx_sz = (size_t)II * HH;        //    524,288
  const size_t h_sz  = (size_t)HH * BB;        //     65,536
  const size_t need  = (xT_sz + 3*wx_sz + 2*h_sz) * sizeof(float) + 512*sizeof(unsigned);
  if (ws_size < need) return;

  float* xT   = ws;
  float* WxTr = xT + xT_sz;
  float* WxTz = WxTr + wx_sz;
  float* WxTh = WxTz + wx_sz;
  float* h    = WxTh + wx_sz;
  float* s    = h + h_sz;
  unsigned* bars = (unsigned*)(s + h_sz);

  k_transpose_x <<<8192, 256, 0, stream>>>(x, xT);
  k_transpose_wx<<<2048, 256, 0, stream>>>(W_rx, WxTr);
  k_transpose_wx<<<2048, 256, 0, stream>>>(W_zx, WxTz);
  k_transpose_wx<<<2048, 256, 0, stream>>>(W_hx, WxTh);
  k_transpose_h0<<< 256, 256, 0, stream>>>(st, h);
  k_init_bars   <<<   1, 512, 0, stream>>>(bars);

  k_gru<<<256, NTHR, 0, stream>>>(xT, WxTr, WxTz, WxTh, h, s,
                                  W_zh, b_z, W_rh, b_r, W_hh, b_h,
                                  W_out, b_out, out, bars);
}